// Round 1
// baseline (540.633 us; speedup 1.0000x reference)
//
#include <hip/hip_runtime.h>

#define D 128
#define KNBR 32
#define BATCH 8192
#define NCLASS 60

// ---------------- K0: wqa[i] = sum_j Wq[i,j]*a[j]; wka[i] = sum_j Wk[i,j]*a[D+j]
__global__ __launch_bounds__(256) void k_prep(const float* __restrict__ Wq,
                                              const float* __restrict__ Wk,
                                              const float* __restrict__ a,
                                              float* __restrict__ wqa,
                                              float* __restrict__ wka) {
    int tid = threadIdx.x;
    int i = tid & 127;
    const float* W  = (tid < 128) ? Wq : Wk;
    const float* av = (tid < 128) ? a  : a + D;
    float s = 0.f;
    for (int j = 0; j < D; ++j) s += W[i * D + j] * av[j];
    if (tid < 128) wqa[i] = s; else wka[i] = s;
}

// ---------------- K1: attention + aggregation per (b, side)
__global__ __launch_bounds__(256) void k_attend(
    const float* __restrict__ mem, const float* __restrict__ Wk,
    const float* __restrict__ wqa, const float* __restrict__ wka,
    const int* __restrict__ src_idxs, const int* __restrict__ dst_idxs,
    const int* __restrict__ src_nb, const int* __restrict__ dst_nb,
    float* __restrict__ selfbuf, float* __restrict__ hbuf)
{
    int b = blockIdx.x;
    int side = blockIdx.y;
    const int* idxs = side ? dst_idxs : src_idxs;
    const int* nbrs = side ? dst_nb  : src_nb;
    int tid = threadIdx.x;

    __shared__ float s_self[D];
    __shared__ float s_wqa[D];
    __shared__ float s_wka[D];
    __shared__ float s_nb[KNBR][D];
    __shared__ int   s_idx[KNBR];
    __shared__ float s_red[D];
    __shared__ float s_skp[KNBR][8];
    __shared__ float s_attn[KNBR];
    __shared__ float s_nbsum[D];
    __shared__ float s_part[2][D];

    int node = idxs[b];
    if (tid < D) { s_self[tid] = mem[(size_t)node * D + tid]; s_wqa[tid] = wqa[tid]; }
    else         { s_wka[tid - D] = wka[tid - D]; }
    if (tid < KNBR) s_idx[tid] = nbrs[b * KNBR + tid];
    __syncthreads();

    // load 32 neighbor rows (2 rows per iteration, coalesced)
    {
        int row = tid >> 7;      // 0 or 1
        int col = tid & 127;
        for (int r = 0; r < KNBR; r += 2) {
            int nn = s_idx[r + row];
            s_nb[r + row][col] = mem[(size_t)nn * D + col];
        }
    }
    // sq partial products
    if (tid < D) s_red[tid] = s_self[tid] * s_wqa[tid];
    __syncthreads();
    for (int s = 64; s > 0; s >>= 1) {
        if (tid < s) s_red[tid] += s_red[tid + s];
        __syncthreads();
    }
    // sk partials: 32 k's x 8 partial threads x 16 elements
    {
        int k = tid >> 3;
        int p = tid & 7;
        float acc = 0.f;
        int c0 = p * 16;
        #pragma unroll
        for (int c = 0; c < 16; ++c) acc += s_nb[k][c0 + c] * s_wka[c0 + c];
        s_skp[k][p] = acc;
    }
    __syncthreads();
    if (tid < KNBR) {
        float sk = 0.f;
        #pragma unroll
        for (int p = 0; p < 8; ++p) sk += s_skp[tid][p];
        float x = s_red[0] + sk;
        s_attn[tid] = (x >= 0.f) ? x : 0.2f * x;   // leaky_relu(0.2)
    }
    __syncthreads();
    if (tid == 0) {
        float m = s_attn[0];
        for (int k = 1; k < KNBR; ++k) m = fmaxf(m, s_attn[k]);
        float sum = 0.f;
        for (int k = 0; k < KNBR; ++k) { float e = expf(s_attn[k] - m); s_attn[k] = e; sum += e; }
        float inv = 1.f / sum;
        for (int k = 0; k < KNBR; ++k) s_attn[k] *= inv;
    }
    __syncthreads();
    // weighted neighbor sum
    if (tid < D) {
        float acc = 0.f;
        #pragma unroll
        for (int k = 0; k < KNBR; ++k) acc += s_attn[k] * s_nb[k][tid];
        s_nbsum[tid] = acc;
    }
    __syncthreads();
    // agg = nbsum @ Wk  (split i-range over two half-warps of threads)
    {
        int j = tid & 127;
        int half = tid >> 7;
        float acc = 0.f;
        for (int i = half * 64; i < half * 64 + 64; ++i)
            acc += s_nbsum[i] * Wk[i * D + j];
        s_part[half][j] = acc;
    }
    __syncthreads();
    size_t base = ((size_t)side * BATCH + b) * D;
    if (tid < D) {
        selfbuf[base + tid] = s_self[tid];
        hbuf[base + tid]    = s_part[0][tid] + s_part[1][tid];
    }
}

// ---------------- K2: edge embedding, 4 rows per block
__global__ __launch_bounds__(256) void k_edge(
    const float* __restrict__ edge_feat, const float* __restrict__ Wew,
    const float* __restrict__ Web, const int* __restrict__ edge_idxs,
    float* __restrict__ ebuf)
{
    int b0 = blockIdx.x * 4;
    int tid = threadIdx.x;
    __shared__ float s_e[4][D];
    __shared__ float s_part[2][4][D];
    {
        int c = tid >> 7;
        int col = tid & 127;
        for (int cc = c; cc < 4; cc += 2) {
            int eidx = edge_idxs[b0 + cc];
            s_e[cc][col] = edge_feat[(size_t)eidx * D + col];
        }
    }
    __syncthreads();
    int j = tid & 127, half = tid >> 7;
    float a0 = 0, a1 = 0, a2 = 0, a3 = 0;
    for (int ii = 0; ii < 64; ++ii) {
        int i = half * 64 + ii;
        float w = Wew[i * D + j];
        a0 += s_e[0][i] * w; a1 += s_e[1][i] * w;
        a2 += s_e[2][i] * w; a3 += s_e[3][i] * w;
    }
    s_part[half][0][j] = a0; s_part[half][1][j] = a1;
    s_part[half][2][j] = a2; s_part[half][3][j] = a3;
    __syncthreads();
    if (tid < D) {
        float bias = Web[tid];
        #pragma unroll
        for (int c = 0; c < 4; ++c)
            ebuf[(size_t)(b0 + c) * D + tid] = s_part[0][c][tid] + s_part[1][c][tid] + bias;
    }
}

// ---------------- K3: msg = relu(cat @ Wuc), 8 rows per block
__global__ __launch_bounds__(256) void k_msg(
    const float* __restrict__ selfbuf, const float* __restrict__ hbuf,
    const float* __restrict__ ebuf, const float* __restrict__ Wuc,
    float* __restrict__ msgbuf)
{
    int side = blockIdx.y;
    int b0 = blockIdx.x * 8;
    int tid = threadIdx.x;
    __shared__ float s_cat[8][512];
    __shared__ float s_part[2][8][D];
    for (int t = tid; t < 8 * 512; t += 256) {
        int c = t >> 9;
        int i = t & 511;
        int bb = b0 + c;
        float v;
        if (i < 128)      v = selfbuf[((size_t)side * BATCH + bb) * D + i];
        else if (i < 256) v = hbuf[((size_t)side * BATCH + bb) * D + (i - 128)];
        else if (i < 384) v = hbuf[((size_t)(1 - side) * BATCH + bb) * D + (i - 256)];
        else              v = ebuf[(size_t)bb * D + (i - 384)];
        s_cat[c][i] = v;
    }
    __syncthreads();
    int j = tid & 127, half = tid >> 7;
    float acc[8] = {0, 0, 0, 0, 0, 0, 0, 0};
    for (int ii = 0; ii < 256; ++ii) {
        int i = half * 256 + ii;
        float w = Wuc[i * D + j];
        #pragma unroll
        for (int c = 0; c < 8; ++c) acc[c] += s_cat[c][i] * w;
    }
    #pragma unroll
    for (int c = 0; c < 8; ++c) s_part[half][c][j] = acc[c];
    __syncthreads();
    for (int t = tid; t < 8 * D; t += 256) {
        int c = t >> 7, j2 = t & 127;
        float v = s_part[0][c][j2] + s_part[1][c][j2];
        msgbuf[((size_t)side * BATCH + (b0 + c)) * D + j2] = fmaxf(v, 0.f);
    }
}

// ---------------- K4: logits = relu(msg @ Wc1) @ Wc2, 4 rows per block
__global__ __launch_bounds__(256) void k_cls(
    const float* __restrict__ msgbuf, const float* __restrict__ Wc1,
    const float* __restrict__ Wc2, float* __restrict__ out)
{
    int side = blockIdx.y;
    int b0 = blockIdx.x * 4;
    int tid = threadIdx.x;
    __shared__ float s_m[4][D];
    __shared__ float s_part[2][4][D];
    __shared__ float s_h1[4][D];
    for (int t = tid; t < 4 * D; t += 256) {
        int c = t >> 7, j = t & 127;
        s_m[c][j] = msgbuf[((size_t)side * BATCH + (b0 + c)) * D + j];
    }
    __syncthreads();
    int j = tid & 127, half = tid >> 7;
    float a0 = 0, a1 = 0, a2 = 0, a3 = 0;
    for (int ii = 0; ii < 64; ++ii) {
        int i = half * 64 + ii;
        float w = Wc1[i * D + j];
        a0 += s_m[0][i] * w; a1 += s_m[1][i] * w;
        a2 += s_m[2][i] * w; a3 += s_m[3][i] * w;
    }
    s_part[half][0][j] = a0; s_part[half][1][j] = a1;
    s_part[half][2][j] = a2; s_part[half][3][j] = a3;
    __syncthreads();
    for (int t = tid; t < 4 * D; t += 256) {
        int c = t >> 7, j2 = t & 127;
        s_h1[c][j2] = fmaxf(s_part[0][c][j2] + s_part[1][c][j2], 0.f);
    }
    __syncthreads();
    if (tid < 4 * NCLASS) {
        int c = tid / NCLASS, j2 = tid % NCLASS;
        float acc = 0.f;
        for (int i = 0; i < D; ++i) acc += s_h1[c][i] * Wc2[i * NCLASS + j2];
        out[((size_t)side * BATCH + (b0 + c)) * NCLASS + j2] = acc;
    }
}

extern "C" void kernel_launch(void* const* d_in, const int* in_sizes, int n_in,
                              void* d_out, int out_size, void* d_ws, size_t ws_size,
                              hipStream_t stream) {
    const float* mem       = (const float*)d_in[0];
    const float* edge_feat = (const float*)d_in[1];
    const float* Wq        = (const float*)d_in[2];
    const float* Wk        = (const float*)d_in[3];
    const float* a         = (const float*)d_in[4];
    const float* Wew       = (const float*)d_in[5];
    const float* Web       = (const float*)d_in[6];
    const float* Wuc       = (const float*)d_in[7];
    const float* Wc1       = (const float*)d_in[8];
    const float* Wc2       = (const float*)d_in[9];
    const int* src_idxs    = (const int*)d_in[10];
    const int* dst_idxs    = (const int*)d_in[11];
    const int* edge_idxs   = (const int*)d_in[12];
    const int* src_nb      = (const int*)d_in[13];
    const int* dst_nb      = (const int*)d_in[14];
    float* out = (float*)d_out;

    float* ws = (float*)d_ws;
    float* wqa     = ws;                       // 128
    float* wka     = ws + 128;                 // 128
    float* selfbuf = ws + 256;                 // 2*B*D
    float* hbuf    = selfbuf + 2 * (size_t)BATCH * D;
    float* ebuf    = hbuf    + 2 * (size_t)BATCH * D;   // B*D
    float* msgbuf  = ebuf    + (size_t)BATCH * D;       // 2*B*D

    k_prep<<<1, 256, 0, stream>>>(Wq, Wk, a, wqa, wka);
    k_attend<<<dim3(BATCH, 2), 256, 0, stream>>>(mem, Wk, wqa, wka,
                                                 src_idxs, dst_idxs, src_nb, dst_nb,
                                                 selfbuf, hbuf);
    k_edge<<<BATCH / 4, 256, 0, stream>>>(edge_feat, Wew, Web, edge_idxs, ebuf);
    k_msg<<<dim3(BATCH / 8, 2), 256, 0, stream>>>(selfbuf, hbuf, ebuf, Wuc, msgbuf);
    k_cls<<<dim3(BATCH / 4, 2), 256, 0, stream>>>(msgbuf, Wc1, Wc2, out);
}